// Round 6
// baseline (22.583 us; speedup 1.0000x reference)
//
#include <hip/hip_runtime.h>
#include <math.h>

#define BB 1024   // batch (rows)
#define NN 64     // dims (cols)

#define LN2F 0.69314718055994530942f
#define BINS 256      // bins per unit interval
#define TW   64       // conv half-window in bins (3.27 sigma at h~0.0766)
#define HSIZE 769     // histogram bins over [-1,2]
#define NOUT 258      // output bins (abs bins 255..512)
#define OBASE 255

// Fused kernel:
//   blocks [0,256):   KNN — 4 query rows each, per-wave selection
//   blocks [256,512): KDE — dim r = (bx-256)>>2, query chunk = (bx-256)&3
__global__ __launch_bounds__(256, 4) void fused_kernel(const float* __restrict__ act,
                                                       const int* __restrict__ kptr,
                                                       float* __restrict__ logrho,
                                                       float* __restrict__ partial) {
    const int bx = blockIdx.x;
    const int tid = threadIdx.x;

    __shared__ float s_d[4096];
    __shared__ float s_x[264];

    if (bx < 256) {
        // ---------------- KNN role: queries qbase..qbase+3 ----------------
        const int qbase = bx * 4;
        if (tid < 64) {
            ((float4*)s_x)[tid] = ((const float4*)(act + (size_t)qbase * NN))[tid];
        }
        __syncthreads();

        #pragma unroll 1
        for (int c = 0; c < 4; ++c) {
            const int j = tid + 256 * c;
            const float4* row = (const float4*)(act + (size_t)j * NN);
            float a0 = 0.f, a1 = 0.f, a2 = 0.f, a3 = 0.f;
            #pragma unroll 2
            for (int d = 0; d < 16; ++d) {
                const float4 v = row[d];
                {   const float4 qq = ((const float4*)s_x)[d];
                    float x0 = v.x - qq.x, x1 = v.y - qq.y, x2 = v.z - qq.z, x3 = v.w - qq.w;
                    a0 += x0 * x0 + x1 * x1 + x2 * x2 + x3 * x3; }
                {   const float4 qq = ((const float4*)s_x)[16 + d];
                    float x0 = v.x - qq.x, x1 = v.y - qq.y, x2 = v.z - qq.z, x3 = v.w - qq.w;
                    a1 += x0 * x0 + x1 * x1 + x2 * x2 + x3 * x3; }
                {   const float4 qq = ((const float4*)s_x)[32 + d];
                    float x0 = v.x - qq.x, x1 = v.y - qq.y, x2 = v.z - qq.z, x3 = v.w - qq.w;
                    a2 += x0 * x0 + x1 * x1 + x2 * x2 + x3 * x3; }
                {   const float4 qq = ((const float4*)s_x)[48 + d];
                    float x0 = v.x - qq.x, x1 = v.y - qq.y, x2 = v.z - qq.z, x3 = v.w - qq.w;
                    a3 += x0 * x0 + x1 * x1 + x2 * x2 + x3 * x3; }
            }
            s_d[0 * 1024 + j] = a0;
            s_d[1 * 1024 + j] = a1;
            s_d[2 * 1024 + j] = a2;
            s_d[3 * 1024 + j] = a3;
        }
        __syncthreads();

        // wave w handles query qbase+w
        const int w = tid >> 6, lane = tid & 63;
        float v[16];
        #pragma unroll
        for (int c = 0; c < 16; ++c) v[c] = s_d[w * 1024 + lane + 64 * c];
        const int kk = kptr[0];
        float last = 0.f;
        for (int e = 0; e <= kk; ++e) {
            float bv = 1e30f; int bi = 0;
            #pragma unroll
            for (int c = 0; c < 16; ++c) { if (v[c] < bv) { bv = v[c]; bi = c; } }
            float mv = bv; int mi = (lane << 4) | bi;
            #pragma unroll
            for (int off = 32; off > 0; off >>= 1) {
                float ov = __shfl_xor(mv, off);
                int   oi = __shfl_xor(mi, off);
                if (ov < mv || (ov == mv && oi < mi)) { mv = ov; mi = oi; }
            }
            last = mv;
            if ((mi >> 4) == lane) v[mi & 15] = 1e30f;
        }
        if (lane == 0) {
            logrho[qbase + w] = __builtin_amdgcn_logf(fmaxf(last, 1e-12f)) * LN2F;
        }
    } else {
        // ---------------- KDE role: dim r, query chunk ----------------
        const int idx = bx - 256;
        const int r = idx >> 2;        // 0..63
        const int chunk = idx & 3;     // 0..3 (256 queries each)

        int*   hint = (int*)s_d;       // [0,769) histogram (int counts)
        float* harr = s_d;             // same storage as float after convert
        float* ktab = s_d + 772;       // 65 floats
        float* outg = s_d + 840;       // 258 floats

        // load column into registers, accumulate stats
        float cv[4];
        float lsum = 0.f, lsq = 0.f;
        #pragma unroll
        for (int c = 0; c < 4; ++c) {
            const int j = tid + 256 * c;
            float v = act[(size_t)j * NN + r];
            cv[c] = v;
            lsum += v; lsq += v * v;
        }
        #pragma unroll
        for (int off = 32; off > 0; off >>= 1) {
            lsum += __shfl_xor(lsum, off);
            lsq  += __shfl_xor(lsq,  off);
        }
        const int wid = tid >> 6;
        if ((tid & 63) == 0) { s_x[wid] = lsum; s_x[4 + wid] = lsq; }

        // zero histogram
        for (int i = tid; i < HSIZE; i += 256) hint[i] = 0;
        __syncthreads();

        const float total = s_x[0] + s_x[1] + s_x[2] + s_x[3];
        const float totsq = s_x[4] + s_x[5] + s_x[6] + s_x[7];
        const float mean = total * (1.f / BB);
        const float var = (totsq - (float)BB * mean * mean) * (1.f / (BB - 1)); // ddof=1
        const float stdv = sqrtf(fmaxf(var, 0.f));
        const float h = fmaxf(1.06f * 0.25f * stdv, 1e-4f);   // 1024^-0.2 = 0.25
        const float ih = 1.f / h;
        const float a  = 0.84932180028801904272f * ih;        // sqrt(0.5*log2 e)/h
        const float ad = a * (1.f / (float)BINS);             // per-bin scale

        // splat source + both reflections (integer counts -> deterministic)
        #pragma unroll
        for (int c = 0; c < 4; ++c) {
            const float x = cv[c];
            int b0 = (int)floorf(x * (float)BINS) + BINS;             // p = x
            int b1 = (int)floorf(-x * (float)BINS) + BINS;            // p = -x
            int b2 = (int)floorf((2.f - x) * (float)BINS) + BINS;     // p = 2-x
            b0 = min(max(b0, 0), HSIZE - 1);
            b1 = min(max(b1, 0), HSIZE - 1);
            b2 = min(max(b2, 0), HSIZE - 1);
            atomicAdd(&hint[b0], 1);
            atomicAdd(&hint[b1], 1);
            atomicAdd(&hint[b2], 1);
        }
        // kernel table K[m] = exp2(-(ad*m)^2)
        if (tid <= TW) {
            const float t = ad * (float)tid;
            ktab[tid] = __builtin_amdgcn_exp2f(-(t * t));
        }
        __syncthreads();

        // convert histogram int -> float in place
        for (int i = tid; i < HSIZE; i += 256) {
            const int c = hint[i];
            harr[i] = (float)c;
        }
        __syncthreads();

        // convolution: outg[o] = sum_{|m|<=TW} hist[OBASE+o+m] * K[|m|]
        for (int o = tid; o < NOUT; o += 256) {
            const float* hp = harr + OBASE + o;
            float acc = hp[0] * ktab[0];
            #pragma unroll 4
            for (int m = 1; m <= TW; ++m)
                acc += (hp[m] + hp[-m]) * ktab[m];
            outg[o] = acc;
        }
        __syncthreads();

        // evaluate density at this chunk's 256 queries (1 per thread)
        const float dscale = 0.39894228040143267794f * ih * (1.f / (float)BB);
        const float x = cv[chunk];
        const float u = fmaf(x, (float)BINS, (float)OBASE + 0.5f);  // grid coord (bin centers)
        const float fu = floorf(u);
        const int i0 = (int)fu - OBASE;
        const float f = u - fu;
        const float dv = outg[i0] + (outg[i0 + 1] - outg[i0]) * f;
        float lp = __builtin_amdgcn_logf(fmaf(dv, dscale, 1e-8f)) * LN2F;

        #pragma unroll
        for (int off = 32; off > 0; off >>= 1) lp += __shfl_xor(lp, off);
        if ((tid & 63) == 0) s_x[8 + wid] = lp;
        __syncthreads();
        if (tid == 0) {
            partial[idx] = s_x[8] + s_x[9] + s_x[10] + s_x[11];   // partial[r*4+chunk]
        }
    }
}

// ---------------- finalize: joint entropy scalar + 64 marginals ----------------
__global__ __launch_bounds__(256) void finalize_kernel(const float* __restrict__ logrho,
                                                       const float* __restrict__ partial,
                                                       const int* __restrict__ kptr,
                                                       double log_c_d, double dg_B,
                                                       float* __restrict__ out) {
    const int tid = threadIdx.x;
    __shared__ double red[256];

    double s = 0.0;
    #pragma unroll
    for (int c = 0; c < 4; ++c) s += (double)logrho[tid + 256 * c];
    red[tid] = s;
    __syncthreads();
    for (int st = 128; st > 0; st >>= 1) { if (tid < st) red[tid] += red[tid + st]; __syncthreads(); }

    if (tid == 0) {
        const int kk = kptr[0];
        double dgk = -0.57721566490153286061;                 // digamma(1)
        for (int t = 1; t < kk; ++t) dgk += 1.0 / (double)t;  // digamma(k)
        const double log_rho_sum = 0.5 * (red[0] / (double)BB);
        const double h_nats = -dgk + dg_B + log_c_d + (double)NN * log_rho_sum;
        out[0] = (float)(h_nats / 0.69314718055994530942);
    }
    if (tid < NN) {
        const float p = partial[tid * 4 + 0] + partial[tid * 4 + 1]
                      + partial[tid * 4 + 2] + partial[tid * 4 + 3];
        out[1 + tid] = -p * (1.0f / (float)BB);
    }
}

extern "C" void kernel_launch(void* const* d_in, const int* in_sizes, int n_in,
                              void* d_out, int out_size, void* d_ws, size_t ws_size,
                              hipStream_t stream) {
    const float* act = (const float*)d_in[0];
    const int* kptr = (const int*)d_in[1];
    float* out = (float*)d_out;

    float* logrho = (float*)d_ws;          // 1024 floats
    float* partial = logrho + BB;          // 256 floats (64 dims x 4 chunks)

    const double log_c_d = 0.5 * (double)NN * log(M_PI) - lgamma((double)NN / 2.0 + 1.0);
    const double xB = (double)BB;          // digamma(1024) via asymptotic series
    const double dg_B = log(xB) - 1.0 / (2.0 * xB) - 1.0 / (12.0 * xB * xB)
                        + 1.0 / (120.0 * xB * xB * xB * xB);

    fused_kernel<<<512, 256, 0, stream>>>(act, kptr, logrho, partial);
    finalize_kernel<<<1, 256, 0, stream>>>(logrho, partial, kptr, log_c_d, dg_B, out);
}